// Round 3
// baseline (175.317 us; speedup 1.0000x reference)
//
#include <hip/hip_runtime.h>
#include <hip/hip_bf16.h>

// B=F=384, H=64, N=F*H=24576, TAU=1, EPS=1e-12
// out[b,f,g] = x[f,g] * softmax_g( qhat[b,f,:] . khat[b,g,:] )

typedef __attribute__((ext_vector_type(8))) short bf16x8;
typedef __attribute__((ext_vector_type(4))) float f32x4;

__device__ __forceinline__ ushort f2bf(float f) {
  union { __hip_bfloat16 h; ushort u; } c;
  c.h = __float2bfloat16(f);
  return c.u;
}

__device__ __forceinline__ void load_lds16(const void* g, void* l) {
  __builtin_amdgcn_global_load_lds(
      (const __attribute__((address_space(1))) void*)g,
      (__attribute__((address_space(3))) void*)l, 16, 0, 0);
}

// ---------------- Kernel 0: x -> bf16, pre-swizzled for global_load_lds ----
__global__ __launch_bounds__(256) void xconv(const float* __restrict__ xin,
                                             ushort* __restrict__ xbf) {
  int t = blockIdx.x * 256 + threadIdx.x;   // 18432 threads, 8 bf16 each
  int o = t * 8;
  int kt = o / 12288;
  int rem = o - kt * 12288;
  int m = rem >> 5;
  int sp = (rem >> 3) & 3;
  int slot = sp ^ ((m >> 1) & 3);
  const float* src = xin + m * 384 + kt * 32 + slot * 8;
  float4 a = *reinterpret_cast<const float4*>(src);
  float4 b = *reinterpret_cast<const float4*>(src + 4);
  ushort4 u0 = make_ushort4(f2bf(a.x), f2bf(a.y), f2bf(a.z), f2bf(a.w));
  ushort4 u1 = make_ushort4(f2bf(b.x), f2bf(b.y), f2bf(b.z), f2bf(b.w));
  *reinterpret_cast<ushort4*>(xbf + o)     = u0;
  *reinterpret_cast<ushort4*>(xbf + o + 4) = u1;
}

// ---------------- Kernel 1: q/k GEMM + L2-normalize -> swizzled bf16 -------
// grid (384, 2): x = head (64 cols of N), y = 0:Q 1:K. 256 thr, 4 waves.
__global__ __launch_bounds__(256) void qk_gemm(
    const ushort* __restrict__ xbf,
    const float* __restrict__ Wq, const float* __restrict__ bq,
    const float* __restrict__ Wk, const float* __restrict__ bk,
    ushort* __restrict__ qhat, ushort* __restrict__ khat)
{
  const int bx = blockIdx.x;
  const int n0 = bx * 64;
  const float* W    = blockIdx.y ? Wk : Wq;
  const float* bias = blockIdx.y ? bk : bq;
  ushort* outp      = blockIdx.y ? khat : qhat;

  __shared__ __align__(16) ushort Alds[384 * 32];  // 24 KB, swizzled-linear
  __shared__ __align__(16) ushort Blds[64 * 40];   // 5 KB, +8 pad

  const int tid  = threadIdx.x;
  const int wave = tid >> 6;
  const int lane = tid & 63;
  const int l15  = lane & 15;
  const int lhi  = lane >> 4;

  f32x4 acc[6][4];
  #pragma unroll
  for (int m = 0; m < 6; ++m)
    #pragma unroll
    for (int n = 0; n < 4; ++n) acc[m][n] = (f32x4)(0.f);

  const int aslot = lhi ^ ((l15 >> 1) & 3);   // A frag read swizzle

  for (int kt = 0; kt < 12; ++kt) {
    const ushort* asrc = xbf + kt * 12288 + lane * 8;
    #pragma unroll
    for (int i = 0; i < 6; ++i) {
      int chunk = wave * 6 + i;
      load_lds16(asrc + chunk * 512, (char*)Alds + chunk * 1024);
    }
    #pragma unroll
    for (int i = 0; i < 2; ++i) {
      int idx = tid + 256 * i;
      int row = idx >> 3, c4 = idx & 7;
      float4 v = *reinterpret_cast<const float4*>(
          W + (size_t)(n0 + row) * 384 + kt * 32 + c4 * 4);
      ushort4 u = make_ushort4(f2bf(v.x), f2bf(v.y), f2bf(v.z), f2bf(v.w));
      *reinterpret_cast<ushort4*>(&Blds[row * 40 + c4 * 4]) = u;
    }
    __syncthreads();

    bf16x8 bfr[4];
    #pragma unroll
    for (int nf = 0; nf < 4; ++nf)
      bfr[nf] = *reinterpret_cast<const bf16x8*>(&Blds[(nf * 16 + l15) * 40 + lhi * 8]);
    #pragma unroll
    for (int mf = 0; mf < 6; ++mf) {
      int rr = wave * 96 + mf * 16 + l15;
      bf16x8 afr = *reinterpret_cast<const bf16x8*>(&Alds[rr * 32 + aslot * 8]);
      #pragma unroll
      for (int nf = 0; nf < 4; ++nf)
        acc[mf][nf] = __builtin_amdgcn_mfma_f32_16x16x32_bf16(afr, bfr[nf], acc[mf][nf], 0, 0, 0);
    }
    __syncthreads();
  }

  // epilogue: +bias, L2-normalize over 64 cols (one head), write swizzled bf16
  float bv[4];
  int hp[4];
  const int sw = bx & 7;
  #pragma unroll
  for (int nf = 0; nf < 4; ++nf) {
    bv[nf] = bias[n0 + nf * 16 + l15];
    hp[nf] = (((nf * 2 + (l15 >> 3)) ^ sw) << 3) + (l15 & 7);  // swizzled h
  }

  #pragma unroll
  for (int mf = 0; mf < 6; ++mf) {
    float ss[4];
    #pragma unroll
    for (int j = 0; j < 4; ++j) {
      float s = 0.f;
      #pragma unroll
      for (int nf = 0; nf < 4; ++nf) {
        float v = acc[mf][nf][j] + bv[nf];
        acc[mf][nf][j] = v;
        s += v * v;
      }
      ss[j] = s;
    }
    #pragma unroll
    for (int m = 1; m < 16; m <<= 1) {
      #pragma unroll
      for (int j = 0; j < 4; ++j) ss[j] += __shfl_xor(ss[j], m, 64);
    }
    #pragma unroll
    for (int j = 0; j < 4; ++j) {
      float scale = 1.f / fmaxf(sqrtf(ss[j]), 1e-12f);
      int row = wave * 96 + mf * 16 + lhi * 4 + j;   // = b index
      #pragma unroll
      for (int nf = 0; nf < 4; ++nf)
        outp[(size_t)row * 24576 + n0 + hp[nf]] = f2bf(acc[mf][nf][j] * scale);
    }
  }
}

// ---------------- Kernel 2: scores + softmax + x*P (transposed MFMA) ------
// 1-D grid 2304, XCD-colocated: blocks of same b land on one XCD's L2.
// Block = 64 f-rows x all 384 g for one b. Wave w owns f-rows f0+16w+l15.
// S^T = mfma(K, Q): lane holds P[f=l15][g = nf*16 + lhi*4 + j] -> in-register
// softmax (2 shfl), direct float4 out stores. LDS = K only, ONE barrier.
__global__ __launch_bounds__(256, 3) void attn_out(
    const float* __restrict__ xin,
    const ushort* __restrict__ qhat,
    const ushort* __restrict__ khat,
    float* __restrict__ out)
{
  const int id = blockIdx.x;
  const int xcd = id & 7;
  const int j_  = id >> 3;              // 0..287
  const int b   = xcd * 48 + j_ / 6;    // 6 consecutive same-XCD blocks per b
  const int f0  = (j_ % 6) * 64;

  __shared__ __align__(16) ushort Klds[384 * 64];   // 48 KB, swizzled

  const int tid  = threadIdx.x;
  const int wave = tid >> 6;
  const int lane = tid & 63;
  const int l15  = lane & 15;
  const int lhi  = lane >> 4;

  // stage khat[b] (48 chunks of 1 KB, 12 per wave)
  const ushort* ksrc = khat + (size_t)b * 24576 + lane * 8;
  #pragma unroll
  for (int i = 0; i < 12; ++i) {
    int chunk = wave * 12 + i;
    load_lds16(ksrc + chunk * 512, (char*)Klds + chunk * 1024);
  }

  // Q fragment (B-operand): row f = f0 + 16*wave + l15; f&7 == l15&7 so the
  // per-row write swizzle cancels with the (l15&7) read XOR.
  const int fr = f0 + wave * 16 + l15;
  bf16x8 q8[2];
  #pragma unroll
  for (int ks = 0; ks < 2; ++ks)
    q8[ks] = *reinterpret_cast<const bf16x8*>(
        qhat + (size_t)b * 24576 + (size_t)fr * 64 + (((ks * 4 + lhi) ^ (l15 & 7)) << 3));
  __syncthreads();

  // S^T: acc[nf] covers g in [16nf, 16nf+16); D[row=g][col=f]
  f32x4 acc[24];
  #pragma unroll
  for (int n = 0; n < 24; ++n) acc[n] = (f32x4)(0.f);

  #pragma unroll
  for (int ks = 0; ks < 2; ++ks) {
    #pragma unroll
    for (int nf = 0; nf < 24; ++nf) {
      bf16x8 kf = *reinterpret_cast<const bf16x8*>(
          &Klds[(nf * 16 + l15) * 64 + (((ks * 4 + lhi) ^ (l15 & 7)) << 3)]);
      acc[nf] = __builtin_amdgcn_mfma_f32_16x16x32_bf16(kf, q8[ks], acc[nf], 0, 0, 0);
    }
  }

  // in-register softmax over g for this lane's f-row (4 parallel chains)
  float m0 = acc[0][0], m1 = acc[0][1], m2 = acc[0][2], m3 = acc[0][3];
  #pragma unroll
  for (int nf = 1; nf < 24; ++nf) {
    m0 = fmaxf(m0, acc[nf][0]); m1 = fmaxf(m1, acc[nf][1]);
    m2 = fmaxf(m2, acc[nf][2]); m3 = fmaxf(m3, acc[nf][3]);
  }
  float m = fmaxf(fmaxf(m0, m1), fmaxf(m2, m3));
  m = fmaxf(m, __shfl_xor(m, 16, 64));
  m = fmaxf(m, __shfl_xor(m, 32, 64));

  float s0 = 0.f, s1 = 0.f, s2 = 0.f, s3 = 0.f;
  #pragma unroll
  for (int nf = 0; nf < 24; ++nf) {
    float p0 = __expf(acc[nf][0] - m);
    float p1 = __expf(acc[nf][1] - m);
    float p2 = __expf(acc[nf][2] - m);
    float p3 = __expf(acc[nf][3] - m);
    acc[nf][0] = p0; acc[nf][1] = p1; acc[nf][2] = p2; acc[nf][3] = p3;
    s0 += p0; s1 += p1; s2 += p2; s3 += p3;
  }
  float s = (s0 + s1) + (s2 + s3);
  s += __shfl_xor(s, 16, 64);
  s += __shfl_xor(s, 32, 64);
  const float inv = 1.f / s;

  // direct store: out[b, fr, g] = x[fr, g] * p * inv ; 4 consecutive g / frag
  const float* xrow = xin + (size_t)fr * 384;
  float* orow = out + (size_t)b * 147456 + (size_t)fr * 384;
  const int c0 = lhi * 4;
  #pragma unroll 4
  for (int nf = 0; nf < 24; ++nf) {
    int c = nf * 16 + c0;
    float4 x4 = *reinterpret_cast<const float4*>(xrow + c);
    float4 o;
    o.x = x4.x * acc[nf][0] * inv;
    o.y = x4.y * acc[nf][1] * inv;
    o.z = x4.z * acc[nf][2] * inv;
    o.w = x4.w * acc[nf][3] * inv;
    *reinterpret_cast<float4*>(orow + c) = o;
  }
}

extern "C" void kernel_launch(void* const* d_in, const int* in_sizes, int n_in,
                              void* d_out, int out_size, void* d_ws, size_t ws_size,
                              hipStream_t stream) {
  const float* x  = (const float*)d_in[0];
  const float* Wq = (const float*)d_in[1];
  const float* bq = (const float*)d_in[2];
  const float* Wk = (const float*)d_in[3];
  const float* bk = (const float*)d_in[4];
  float* out = (float*)d_out;

  ushort* qhat = (ushort*)d_ws;
  ushort* khat = qhat + (size_t)384 * 24576;
  ushort* xbf  = khat + (size_t)384 * 24576;

  xconv<<<dim3(72), dim3(256), 0, stream>>>(x, xbf);

  dim3 g1(384, 2), b1(256);
  qk_gemm<<<g1, b1, 0, stream>>>(xbf, Wq, bq, Wk, bk, qhat, khat);

  attn_out<<<dim3(2304), dim3(256), 0, stream>>>(x, qhat, khat, out);
}

// Round 4
// 113.220 us; speedup vs baseline: 1.5485x; 1.5485x over previous
//
#include <hip/hip_runtime.h>
#include <hip/hip_bf16.h>

// B=F=384, H=64, N=F*H=24576, TAU=1, EPS=1e-12
// out[b,f,g] = x[f,g] * softmax_g( qhat[b,f,:] . khat[b,g,:] )

typedef __attribute__((ext_vector_type(8))) short bf16x8;
typedef __attribute__((ext_vector_type(4))) float f32x4;

__device__ __forceinline__ ushort f2bf(float f) {
  union { __hip_bfloat16 h; ushort u; } c;
  c.h = __float2bfloat16(f);
  return c.u;
}

__device__ __forceinline__ void load_lds16(const void* g, void* l) {
  __builtin_amdgcn_global_load_lds(
      (const __attribute__((address_space(1))) void*)g,
      (__attribute__((address_space(3))) void*)l, 16, 0, 0);
}

// ---------------- Kernel 0: x -> bf16, pre-swizzled for global_load_lds ----
__global__ __launch_bounds__(256) void xconv(const float* __restrict__ xin,
                                             ushort* __restrict__ xbf) {
  int t = blockIdx.x * 256 + threadIdx.x;   // 18432 threads, 8 bf16 each
  int o = t * 8;
  int kt = o / 12288;
  int rem = o - kt * 12288;
  int m = rem >> 5;
  int sp = (rem >> 3) & 3;
  int slot = sp ^ ((m >> 1) & 3);
  const float* src = xin + m * 384 + kt * 32 + slot * 8;
  float4 a = *reinterpret_cast<const float4*>(src);
  float4 b = *reinterpret_cast<const float4*>(src + 4);
  ushort4 u0 = make_ushort4(f2bf(a.x), f2bf(a.y), f2bf(a.z), f2bf(a.w));
  ushort4 u1 = make_ushort4(f2bf(b.x), f2bf(b.y), f2bf(b.z), f2bf(b.w));
  *reinterpret_cast<ushort4*>(xbf + o)     = u0;
  *reinterpret_cast<ushort4*>(xbf + o + 4) = u1;
}

// ---------------- Kernel 1: q/k GEMM + L2-normalize -> swizzled bf16 -------
// grid (384, 2): x = head (64 cols of N), y = 0:Q 1:K. 256 thr, 4 waves.
__global__ __launch_bounds__(256) void qk_gemm(
    const ushort* __restrict__ xbf,
    const float* __restrict__ Wq, const float* __restrict__ bq,
    const float* __restrict__ Wk, const float* __restrict__ bk,
    ushort* __restrict__ qhat, ushort* __restrict__ khat)
{
  const int bx = blockIdx.x;
  const int n0 = bx * 64;
  const float* W    = blockIdx.y ? Wk : Wq;
  const float* bias = blockIdx.y ? bk : bq;
  ushort* outp      = blockIdx.y ? khat : qhat;

  __shared__ __align__(16) ushort Alds[384 * 32];  // 24 KB, swizzled-linear
  __shared__ __align__(16) ushort Blds[64 * 40];   // 5 KB, +8 pad

  const int tid  = threadIdx.x;
  const int wave = tid >> 6;
  const int lane = tid & 63;
  const int l15  = lane & 15;
  const int lhi  = lane >> 4;

  f32x4 acc[6][4];
  #pragma unroll
  for (int m = 0; m < 6; ++m)
    #pragma unroll
    for (int n = 0; n < 4; ++n) acc[m][n] = (f32x4)(0.f);

  const int aslot = lhi ^ ((l15 >> 1) & 3);   // A frag read swizzle

  for (int kt = 0; kt < 12; ++kt) {
    const ushort* asrc = xbf + kt * 12288 + lane * 8;
    #pragma unroll
    for (int i = 0; i < 6; ++i) {
      int chunk = wave * 6 + i;
      load_lds16(asrc + chunk * 512, (char*)Alds + chunk * 1024);
    }
    #pragma unroll
    for (int i = 0; i < 2; ++i) {
      int idx = tid + 256 * i;
      int row = idx >> 3, c4 = idx & 7;
      float4 v = *reinterpret_cast<const float4*>(
          W + (size_t)(n0 + row) * 384 + kt * 32 + c4 * 4);
      ushort4 u = make_ushort4(f2bf(v.x), f2bf(v.y), f2bf(v.z), f2bf(v.w));
      *reinterpret_cast<ushort4*>(&Blds[row * 40 + c4 * 4]) = u;
    }
    __syncthreads();

    bf16x8 bfr[4];
    #pragma unroll
    for (int nf = 0; nf < 4; ++nf)
      bfr[nf] = *reinterpret_cast<const bf16x8*>(&Blds[(nf * 16 + l15) * 40 + lhi * 8]);
    #pragma unroll
    for (int mf = 0; mf < 6; ++mf) {
      int rr = wave * 96 + mf * 16 + l15;
      bf16x8 afr = *reinterpret_cast<const bf16x8*>(&Alds[rr * 32 + aslot * 8]);
      #pragma unroll
      for (int nf = 0; nf < 4; ++nf)
        acc[mf][nf] = __builtin_amdgcn_mfma_f32_16x16x32_bf16(afr, bfr[nf], acc[mf][nf], 0, 0, 0);
    }
    __syncthreads();
  }

  // epilogue: +bias, L2-normalize over 64 cols (one head), write swizzled bf16
  float bv[4];
  int hp[4];
  const int sw = bx & 7;
  #pragma unroll
  for (int nf = 0; nf < 4; ++nf) {
    bv[nf] = bias[n0 + nf * 16 + l15];
    hp[nf] = (((nf * 2 + (l15 >> 3)) ^ sw) << 3) + (l15 & 7);  // swizzled h
  }

  #pragma unroll
  for (int mf = 0; mf < 6; ++mf) {
    float ss[4];
    #pragma unroll
    for (int j = 0; j < 4; ++j) {
      float s = 0.f;
      #pragma unroll
      for (int nf = 0; nf < 4; ++nf) {
        float v = acc[mf][nf][j] + bv[nf];
        acc[mf][nf][j] = v;
        s += v * v;
      }
      ss[j] = s;
    }
    #pragma unroll
    for (int m = 1; m < 16; m <<= 1) {
      #pragma unroll
      for (int j = 0; j < 4; ++j) ss[j] += __shfl_xor(ss[j], m, 64);
    }
    #pragma unroll
    for (int j = 0; j < 4; ++j) {
      float scale = 1.f / fmaxf(sqrtf(ss[j]), 1e-12f);
      int row = wave * 96 + mf * 16 + lhi * 4 + j;   // = b index
      #pragma unroll
      for (int nf = 0; nf < 4; ++nf)
        outp[(size_t)row * 24576 + n0 + hp[nf]] = f2bf(acc[mf][nf][j] * scale);
    }
  }
}

// ---------------- Kernel 2: scores + softmax + x*P ------------------------
// 1-D grid 2304, XCD-colocated (6 consecutive same-XCD blocks share one b).
// Block = 64 f-rows x all 384 g. Wave w owns f-rows f0+16w+l15.
// S^T = mfma(K, Q): lane holds P[f][g=nf*16+lhi*4+j] -> in-register softmax
// (zero barriers). Store path: P*inv repacked via LDS overlay in two 32-row
// chunks -> fully contiguous float4 stores (full 128B lines, no write-allocate).
#define PSTR 392
__global__ __launch_bounds__(256, 3) void attn_out(
    const float* __restrict__ xin,
    const ushort* __restrict__ qhat,
    const ushort* __restrict__ khat,
    float* __restrict__ out)
{
  const int id  = blockIdx.x;
  const int xcd = id & 7;
  const int j_  = id >> 3;              // 0..287
  const int b   = xcd * 48 + j_ / 6;
  const int f0  = (j_ % 6) * 64;

  // union: K bf16 [384][64] swizzled (48 KB) | P f32 [32][PSTR] (49 KB)
  __shared__ __align__(16) char smem[32 * PSTR * 4];
  ushort* Klds = reinterpret_cast<ushort*>(smem);
  float*  Slds = reinterpret_cast<float*>(smem);

  const int tid  = threadIdx.x;
  const int wave = tid >> 6;
  const int lane = tid & 63;
  const int l15  = lane & 15;
  const int lhi  = lane >> 4;

  // stage khat[b] (48 chunks of 1 KB, 12 per wave)
  const ushort* ksrc = khat + (size_t)b * 24576 + lane * 8;
  #pragma unroll
  for (int i = 0; i < 12; ++i) {
    int chunk = wave * 12 + i;
    load_lds16(ksrc + chunk * 512, (char*)Klds + chunk * 1024);
  }

  // Q fragment (B-operand): row f = f0 + 16*wave + l15 (f&7 == l15&7, so the
  // per-row write swizzle cancels with the (l15&7) read XOR)
  const int fr = f0 + wave * 16 + l15;
  bf16x8 q8[2];
  #pragma unroll
  for (int ks = 0; ks < 2; ++ks)
    q8[ks] = *reinterpret_cast<const bf16x8*>(
        qhat + (size_t)b * 24576 + (size_t)fr * 64 + (((ks * 4 + lhi) ^ (l15 & 7)) << 3));
  __syncthreads();

  // S^T: acc[nf] covers g in [16nf, 16nf+16); D[row=g][col=f]
  f32x4 acc[24];
  #pragma unroll
  for (int n = 0; n < 24; ++n) acc[n] = (f32x4)(0.f);

  #pragma unroll
  for (int ks = 0; ks < 2; ++ks) {
    #pragma unroll
    for (int nf = 0; nf < 24; ++nf) {
      bf16x8 kf = *reinterpret_cast<const bf16x8*>(
          &Klds[(nf * 16 + l15) * 64 + (((ks * 4 + lhi) ^ (l15 & 7)) << 3)]);
      acc[nf] = __builtin_amdgcn_mfma_f32_16x16x32_bf16(kf, q8[ks], acc[nf], 0, 0, 0);
    }
  }

  // in-register softmax over g for this lane's f-row (4 parallel chains)
  float m0 = acc[0][0], m1 = acc[0][1], m2 = acc[0][2], m3 = acc[0][3];
  #pragma unroll
  for (int nf = 1; nf < 24; ++nf) {
    m0 = fmaxf(m0, acc[nf][0]); m1 = fmaxf(m1, acc[nf][1]);
    m2 = fmaxf(m2, acc[nf][2]); m3 = fmaxf(m3, acc[nf][3]);
  }
  float m = fmaxf(fmaxf(m0, m1), fmaxf(m2, m3));
  m = fmaxf(m, __shfl_xor(m, 16, 64));
  m = fmaxf(m, __shfl_xor(m, 32, 64));

  float s0 = 0.f, s1 = 0.f, s2 = 0.f, s3 = 0.f;
  #pragma unroll
  for (int nf = 0; nf < 24; ++nf) {
    float p0 = __expf(acc[nf][0] - m);
    float p1 = __expf(acc[nf][1] - m);
    float p2 = __expf(acc[nf][2] - m);
    float p3 = __expf(acc[nf][3] - m);
    acc[nf][0] = p0; acc[nf][1] = p1; acc[nf][2] = p2; acc[nf][3] = p3;
    s0 += p0; s1 += p1; s2 += p2; s3 += p3;
  }
  float s = (s0 + s1) + (s2 + s3);
  s += __shfl_xor(s, 16, 64);
  s += __shfl_xor(s, 32, 64);
  const float inv = 1.f / s;

  __syncthreads();   // all K reads done -> P may overlay Klds

  // two 32-row chunks: waves {0,1} own rows f0..f0+31, waves {2,3} the rest
  #pragma unroll
  for (int half = 0; half < 2; ++half) {
    if ((wave >> 1) == half) {
      const int prow = (wave & 1) * 16 + l15;
      #pragma unroll
      for (int nf = 0; nf < 24; ++nf) {
        f32x4 v;
        v[0] = acc[nf][0] * inv; v[1] = acc[nf][1] * inv;
        v[2] = acc[nf][2] * inv; v[3] = acc[nf][3] * inv;
        *reinterpret_cast<f32x4*>(&Slds[prow * PSTR + nf * 16 + lhi * 4]) = v;
      }
    }
    __syncthreads();

    // contiguous read + store: 32 rows x 96 float4 (48 KB contiguous in out)
    const int rbase = f0 + half * 32;
    const float* xsrc = xin + (size_t)rbase * 384;
    float* odst = out + (size_t)b * 147456 + (size_t)rbase * 384;
    #pragma unroll
    for (int i = 0; i < 12; ++i) {
      int idx = tid + 256 * i;
      int row = idx / 96, c = idx - row * 96;
      float4 p4 = *reinterpret_cast<const float4*>(&Slds[row * PSTR + c * 4]);
      float4 x4 = *reinterpret_cast<const float4*>(xsrc + row * 384 + c * 4);
      float4 o;
      o.x = x4.x * p4.x;  o.y = x4.y * p4.y;
      o.z = x4.z * p4.z;  o.w = x4.w * p4.w;
      *reinterpret_cast<float4*>(odst + row * 384 + c * 4) = o;
    }
    if (half == 0) __syncthreads();   // before chunk-B overlay write
  }
}

extern "C" void kernel_launch(void* const* d_in, const int* in_sizes, int n_in,
                              void* d_out, int out_size, void* d_ws, size_t ws_size,
                              hipStream_t stream) {
  const float* x  = (const float*)d_in[0];
  const float* Wq = (const float*)d_in[1];
  const float* bq = (const float*)d_in[2];
  const float* Wk = (const float*)d_in[3];
  const float* bk = (const float*)d_in[4];
  float* out = (float*)d_out;

  ushort* qhat = (ushort*)d_ws;
  ushort* khat = qhat + (size_t)384 * 24576;
  ushort* xbf  = khat + (size_t)384 * 24576;

  xconv<<<dim3(72), dim3(256), 0, stream>>>(x, xbf);

  dim3 g1(384, 2), b1(256);
  qk_gemm<<<g1, b1, 0, stream>>>(xbf, Wq, bq, Wk, bk, qhat, khat);

  attn_out<<<dim3(2304), dim3(256), 0, stream>>>(x, qhat, khat, out);
}